// Round 3
// baseline (101.095 us; speedup 1.0000x reference)
//
#include <hip/hip_runtime.h>
#include <hip/hip_bf16.h>

// Problem constants
constexpr int BN = 16384;          // batch
constexpr int DN = 64;             // nodes / input dim
constexpr int HN = 64;             // hidden
constexpr int XELEMS  = BN * DN;        // 1048576
constexpr int W1ELEMS = DN * HN * DN;   // 262144
constexpr int XCH = XELEMS / 4;         // float4 chunks of X
constexpr int WCH = W1ELEMS / 4;        // float4 chunks of W1

typedef __attribute__((ext_vector_type(8))) short short8;   // 8 x bf16 (4 VGPRs)
typedef __attribute__((ext_vector_type(4))) float f32x4;    // MFMA accumulator

__device__ __forceinline__ unsigned short f2bf(float f) {
    __hip_bfloat16 h = __float2bfloat16(f);
    return *reinterpret_cast<unsigned short*>(&h);
}

// VALU cross-lane reduce: x += rotate_within_16(x, N) via DPP row_ror.
// After ror:8,4,2,1 every lane of each 16-lane row holds the row's full sum
// (butterfly-equivalent; direction-agnostic). Pure VALU — no DS pipe.
#define DPP_ROR_ADD(x, N)                                                     \
    x += __int_as_float(__builtin_amdgcn_update_dpp(                          \
            0, __float_as_int(x), 0x120 + (N), 0xf, 0xf, false))

// ---------------------------------------------------------------------------
// Prep: cast X -> bf16, and W1 * adjacency -> bf16, into workspace.
// ---------------------------------------------------------------------------
__global__ __launch_bounds__(256) void prep_kernel(
    const float* __restrict__ X, const float* __restrict__ adj,
    const float* __restrict__ W1,
    unsigned short* __restrict__ Xbf, unsigned short* __restrict__ W1bf)
{
    int t = blockIdx.x * 256 + threadIdx.x;
    if (t < XCH) {
        float4 v = reinterpret_cast<const float4*>(X)[t];
        ushort4 o;
        o.x = f2bf(v.x); o.y = f2bf(v.y); o.z = f2bf(v.z); o.w = f2bf(v.w);
        reinterpret_cast<ushort4*>(Xbf)[t] = o;
    } else {
        int c = t - XCH;
        if (c < WCH) {
            int flat = c * 4;
            int i = flat >> 12;        // node index = / (H*D)
            int d = flat & 63;         // within-row offset (contiguous dim)
            float4 w = reinterpret_cast<const float4*>(W1)[c];
            float4 a = *reinterpret_cast<const float4*>(adj + i * DN + d);
            ushort4 o;
            o.x = f2bf(w.x * a.x); o.y = f2bf(w.y * a.y);
            o.z = f2bf(w.z * a.z); o.w = f2bf(w.w * a.w);
            reinterpret_cast<ushort4*>(W1bf)[c] = o;
        }
    }
}

// ---------------------------------------------------------------------------
// Main: block = (128-row batch tile, group of 8 nodes). 4 waves x 32 rows.
// A-fragments loaded once per wave, reused across the 8-node loop.
// Per node: B-loads + 16 MFMAs, epilogue = relu*W2 fma + DPP row_ror
// reduction (VALU only, no DS), stage scalar outputs in LDS, one barrier,
// cooperative float4 store.
// ---------------------------------------------------------------------------
__global__ __launch_bounds__(256, 4) void mlp_kernel(
    const unsigned short* __restrict__ Xbf,    // [B][64] bf16
    const unsigned short* __restrict__ W1bf,   // [D][H][64] bf16 (adj folded)
    const float* __restrict__ W2,              // [D][H] fp32
    float* __restrict__ out)                   // [B][D] fp32
{
    const int ng    = blockIdx.x & 7;          // node group (8 nodes)
    const int btile = blockIdx.x >> 3;         // 128-row batch tile
    const int wave  = threadIdx.x >> 6;        // 0..3
    const int lane  = threadIdx.x & 63;
    const int row16 = lane & 15;               // A/B frag row, C/D column (h)
    const int quad  = lane >> 4;               // A/B k-quad, C/D row-quad (b)

    __shared__ float lds_out[128][8];          // [row][node-in-group]

    const int b0 = btile * 128 + wave * 32;

    // A frags: X[b0 + mt*16 + row16][kk*32 + quad*8 ..+8], loaded once
    const unsigned short* aBase = Xbf + (size_t)(b0 + row16) * DN + quad * 8;
    short8 afrag[2][2];
#pragma unroll
    for (int mt = 0; mt < 2; ++mt)
#pragma unroll
        for (int kk = 0; kk < 2; ++kk)
            afrag[mt][kk] = *reinterpret_cast<const short8*>(aBase + mt * 16 * DN + kk * 32);

    for (int j = 0; j < 8; ++j) {
        const int node = ng * 8 + j;
        const unsigned short* bBase = W1bf + (size_t)node * (HN * DN)
                                    + (size_t)row16 * DN + quad * 8;

        f32x4 acc[2][4];
#pragma unroll
        for (int mt = 0; mt < 2; ++mt)
#pragma unroll
            for (int nt = 0; nt < 4; ++nt)
                acc[mt][nt] = (f32x4){0.f, 0.f, 0.f, 0.f};

        // B loaded per-kk to keep only 16 B-VGPRs live at a time
#pragma unroll
        for (int kk = 0; kk < 2; ++kk) {
            short8 bfrag[4];
#pragma unroll
            for (int nt = 0; nt < 4; ++nt)
                bfrag[nt] = *reinterpret_cast<const short8*>(bBase + nt * 16 * DN + kk * 32);
#pragma unroll
            for (int nt = 0; nt < 4; ++nt) {
                acc[0][nt] = __builtin_amdgcn_mfma_f32_16x16x32_bf16(afrag[0][kk], bfrag[nt], acc[0][nt], 0, 0, 0);
                acc[1][nt] = __builtin_amdgcn_mfma_f32_16x16x32_bf16(afrag[1][kk], bfrag[nt], acc[1][nt], 0, 0, 0);
            }
        }

        // epilogue: out[b,node] = sum_h relu(H[b,h]) * W2[node,h]
        // C/D layout: h = nt*16 + row16, b = mt*16 + quad*4 + reg
        float w2v[4];
#pragma unroll
        for (int nt = 0; nt < 4; ++nt)
            w2v[nt] = W2[node * HN + nt * 16 + row16];

#pragma unroll
        for (int mt = 0; mt < 2; ++mt) {
            float p[4] = {0.f, 0.f, 0.f, 0.f};
#pragma unroll
            for (int nt = 0; nt < 4; ++nt)
#pragma unroll
                for (int r = 0; r < 4; ++r)
                    p[r] = fmaf(fmaxf(acc[mt][nt][r], 0.f), w2v[nt], p[r]);
            // 16-lane row reduction, pure VALU (DPP row_ror)
#pragma unroll
            for (int r = 0; r < 4; ++r) {
                DPP_ROR_ADD(p[r], 8);
                DPP_ROR_ADD(p[r], 4);
                DPP_ROR_ADD(p[r], 2);
                DPP_ROR_ADD(p[r], 1);
            }
            // every lane now has all 4 row-sums; lanes row16<4 each store one
            if (row16 < 4)
                lds_out[wave * 32 + mt * 16 + quad * 4 + row16][j] = p[row16];
        }
    }

    __syncthreads();
    // cooperative coalesced store: 128 rows x 8 floats = 256 float4
    {
        int t = threadIdx.x;
        int row = t >> 1, c = t & 1;
        float4 v = *reinterpret_cast<const float4*>(&lds_out[row][c * 4]);
        *reinterpret_cast<float4*>(out + (size_t)(btile * 128 + row) * DN + ng * 8 + c * 4) = v;
    }
}

extern "C" void kernel_launch(void* const* d_in, const int* in_sizes, int n_in,
                              void* d_out, int out_size, void* d_ws, size_t ws_size,
                              hipStream_t stream) {
    const float* X   = (const float*)d_in[0];   // [B, D] fp32
    const float* adj = (const float*)d_in[1];   // [D, D] fp32
    const float* W1  = (const float*)d_in[2];   // [D, H, D] fp32
    const float* W2  = (const float*)d_in[3];   // [D, H] fp32
    float* out = (float*)d_out;                 // [B, D] fp32

    unsigned short* Xbf  = (unsigned short*)d_ws;           // 2 MB
    unsigned short* W1bf = Xbf + XELEMS;                    // 512 KB

    prep_kernel<<<(XCH + WCH + 255) / 256, 256, 0, stream>>>(X, adj, W1, Xbf, W1bf);
    mlp_kernel<<<(BN / 128) * 8, 256, 0, stream>>>(Xbf, W1bf, W2, out);
}

// Round 4
// 81.526 us; speedup vs baseline: 1.2400x; 1.2400x over previous
//
#include <hip/hip_runtime.h>
#include <hip/hip_bf16.h>

// Problem constants
constexpr int BN = 16384;          // batch
constexpr int DN = 64;             // nodes / input dim
constexpr int HN = 64;             // hidden
constexpr int XELEMS  = BN * DN;        // 1048576
constexpr int W1ELEMS = DN * HN * DN;   // 262144
constexpr int XCH = XELEMS / 4;         // float4 chunks of X
constexpr int WCH = W1ELEMS / 4;        // float4 chunks of W1

typedef __attribute__((ext_vector_type(8))) short short8;   // 8 x bf16 (4 VGPRs)
typedef __attribute__((ext_vector_type(4))) float f32x4;    // MFMA accumulator

__device__ __forceinline__ unsigned short f2bf(float f) {
    __hip_bfloat16 h = __float2bfloat16(f);
    return *reinterpret_cast<unsigned short*>(&h);
}

// VALU cross-lane reduce over each 16-lane row: x += row_ror(x, N). After
// ror 8,4,2,1 every lane holds the 16-lane row sum. Pure VALU, no DS pipe.
#define DPP_ROR_ADD(x, N)                                                     \
    x += __int_as_float(__builtin_amdgcn_update_dpp(                          \
            0, __float_as_int(x), 0x120 + (N), 0xf, 0xf, false))

// ---------------------------------------------------------------------------
// Prep: cast X -> bf16, and W1 * adjacency -> bf16, into workspace.
// ---------------------------------------------------------------------------
__global__ __launch_bounds__(256) void prep_kernel(
    const float* __restrict__ X, const float* __restrict__ adj,
    const float* __restrict__ W1,
    unsigned short* __restrict__ Xbf, unsigned short* __restrict__ W1bf)
{
    int t = blockIdx.x * 256 + threadIdx.x;
    if (t < XCH) {
        float4 v = reinterpret_cast<const float4*>(X)[t];
        ushort4 o;
        o.x = f2bf(v.x); o.y = f2bf(v.y); o.z = f2bf(v.z); o.w = f2bf(v.w);
        reinterpret_cast<ushort4*>(Xbf)[t] = o;
    } else {
        int c = t - XCH;
        if (c < WCH) {
            int flat = c * 4;
            int i = flat >> 12;        // node index
            int d = flat & 63;         // within-row offset
            float4 w = reinterpret_cast<const float4*>(W1)[c];
            float4 a = *reinterpret_cast<const float4*>(adj + i * DN + d);
            ushort4 o;
            o.x = f2bf(w.x * a.x); o.y = f2bf(w.y * a.y);
            o.z = f2bf(w.z * a.z); o.w = f2bf(w.w * a.w);
            reinterpret_cast<ushort4*>(W1bf)[c] = o;
        }
    }
}

// ---------------------------------------------------------------------------
// Main: block = (128-row batch tile, group of 4 nodes). 4 waves x 32 rows.
// Stage W1'[4 nodes] (32 KB, XOR-swizzled) + W2 (1 KB) into LDS once, then
// the j-loop touches ONLY LDS + MFMA + VALU (no global loads in the loop).
// Epilogue: relu*W2 (tree), DPP row reduction, LDS transpose, float4 store.
// ---------------------------------------------------------------------------
__global__ __launch_bounds__(256, 4) void mlp_kernel(
    const unsigned short* __restrict__ Xbf,    // [B][64] bf16
    const unsigned short* __restrict__ W1bf,   // [D][H][64] bf16 (adj folded)
    const float* __restrict__ W2,              // [D][H] fp32
    float* __restrict__ out)                   // [B][D] fp32
{
    const int ng    = blockIdx.x & 15;         // node group (4 nodes)
    const int btile = blockIdx.x >> 4;         // 128-row batch tile
    const int wave  = threadIdx.x >> 6;        // 0..3
    const int lane  = threadIdx.x & 63;
    const int row16 = lane & 15;               // A/B frag row, C/D column (h)
    const int quad  = lane >> 4;               // A/B k-quad, C/D row-quad (b)

    __shared__ unsigned short ldsW1[4 * HN * DN];  // 32 KB, swizzled
    __shared__ float ldsW2[4 * HN];                // 1 KB
    __shared__ float lds_out[128][4];              // 2 KB

    // ---- A fragments (one-time global load; overlaps staging) ----
    const int b0 = btile * 128 + wave * 32;
    const unsigned short* aBase = Xbf + (size_t)(b0 + row16) * DN + quad * 8;
    short8 afrag[2][2];
#pragma unroll
    for (int mt = 0; mt < 2; ++mt)
#pragma unroll
        for (int kk = 0; kk < 2; ++kk)
            afrag[mt][kk] = *reinterpret_cast<const short8*>(aBase + mt * 16 * DN + kk * 32);

    // ---- Stage W1' (4 nodes = 2048 x 16B chunks) swizzled into LDS ----
    // chunk (node_local, h, c) -> lds offset node*8192B + h*128B + (c^(h&7))*16B
    {
        const unsigned short* gsrc = W1bf + (size_t)ng * (4 * HN * DN);
#pragma unroll
        for (int it = 0; it < 8; ++it) {
            int chunk = it * 256 + threadIdx.x;      // 0..2047
            int nl = chunk >> 9;                     // node_local
            int rem = chunk & 511;
            int h = rem >> 3;
            int c = rem & 7;
            short8 v = *reinterpret_cast<const short8*>(gsrc + chunk * 8);
            int elem = nl * 4096 + h * 64 + ((c ^ (h & 7)) << 3);
            *reinterpret_cast<short8*>(&ldsW1[elem]) = v;
        }
        if (threadIdx.x < 256)
            ldsW2[threadIdx.x] = W2[ng * 256 + threadIdx.x];
    }
    __syncthreads();

    // ---- j-loop: LDS-only operands ----
    for (int j = 0; j < 4; ++j) {
        // B frags (swizzled ds_read_b128, conflict-free)
        short8 bfrag[2][4];
#pragma unroll
        for (int kk = 0; kk < 2; ++kk)
#pragma unroll
            for (int nt = 0; nt < 4; ++nt) {
                int h = nt * 16 + row16;
                int elem = j * 4096 + h * 64 + (((kk * 4 + quad) ^ (row16 & 7)) << 3);
                bfrag[kk][nt] = *reinterpret_cast<const short8*>(&ldsW1[elem]);
            }

        float w2v[4];
#pragma unroll
        for (int nt = 0; nt < 4; ++nt)
            w2v[nt] = ldsW2[j * 64 + nt * 16 + row16];

        f32x4 acc[2][4];
#pragma unroll
        for (int mt = 0; mt < 2; ++mt)
#pragma unroll
            for (int nt = 0; nt < 4; ++nt)
                acc[mt][nt] = (f32x4){0.f, 0.f, 0.f, 0.f};

#pragma unroll
        for (int kk = 0; kk < 2; ++kk)
#pragma unroll
            for (int nt = 0; nt < 4; ++nt) {
                acc[0][nt] = __builtin_amdgcn_mfma_f32_16x16x32_bf16(afrag[0][kk], bfrag[kk][nt], acc[0][nt], 0, 0, 0);
                acc[1][nt] = __builtin_amdgcn_mfma_f32_16x16x32_bf16(afrag[1][kk], bfrag[kk][nt], acc[1][nt], 0, 0, 0);
            }

        // epilogue: out[b,node] = sum_h relu(H[b,h]) * W2[node,h]
        // C/D layout: h = nt*16 + row16, b = mt*16 + quad*4 + reg
#pragma unroll
        for (int mt = 0; mt < 2; ++mt) {
            float p[4];
#pragma unroll
            for (int r = 0; r < 4; ++r) {
                float q0 = fmaxf(acc[mt][0][r], 0.f) * w2v[0];
                float q1 = fmaxf(acc[mt][1][r], 0.f) * w2v[1];
                q0 = fmaf(fmaxf(acc[mt][2][r], 0.f), w2v[2], q0);
                q1 = fmaf(fmaxf(acc[mt][3][r], 0.f), w2v[3], q1);
                p[r] = q0 + q1;
                DPP_ROR_ADD(p[r], 8);
                DPP_ROR_ADD(p[r], 4);
                DPP_ROR_ADD(p[r], 2);
                DPP_ROR_ADD(p[r], 1);
            }
            if (row16 < 4)
                lds_out[wave * 32 + mt * 16 + quad * 4 + row16][j] = p[row16];
        }
    }

    __syncthreads();
    // cooperative store: 128 rows x 4 floats; thread t stores row t's float4
    if (threadIdx.x < 128) {
        int row = threadIdx.x;
        float4 v = *reinterpret_cast<const float4*>(&lds_out[row][0]);
        *reinterpret_cast<float4*>(out + (size_t)(btile * 128 + row) * DN + ng * 4) = v;
    }
}

extern "C" void kernel_launch(void* const* d_in, const int* in_sizes, int n_in,
                              void* d_out, int out_size, void* d_ws, size_t ws_size,
                              hipStream_t stream) {
    const float* X   = (const float*)d_in[0];   // [B, D] fp32
    const float* adj = (const float*)d_in[1];   // [D, D] fp32
    const float* W1  = (const float*)d_in[2];   // [D, H, D] fp32
    const float* W2  = (const float*)d_in[3];   // [D, H] fp32
    float* out = (float*)d_out;                 // [B, D] fp32

    unsigned short* Xbf  = (unsigned short*)d_ws;           // 2 MB
    unsigned short* W1bf = Xbf + XELEMS;                    // 512 KB

    prep_kernel<<<(XCH + WCH + 255) / 256, 256, 0, stream>>>(X, adj, W1, Xbf, W1bf);
    mlp_kernel<<<(BN / 128) * 16, 256, 0, stream>>>(Xbf, W1bf, W2, out);
}

// Round 5
// 78.718 us; speedup vs baseline: 1.2843x; 1.0357x over previous
//
#include <hip/hip_runtime.h>
#include <hip/hip_bf16.h>

// Problem constants
constexpr int BN = 16384;          // batch
constexpr int DN = 64;             // nodes / input dim
constexpr int HN = 64;             // hidden
constexpr int W1ELEMS = DN * HN * DN;   // 262144
constexpr int WCH = W1ELEMS / 4;        // float4 chunks of W1 (65536)

typedef __attribute__((ext_vector_type(8))) short short8;   // 8 x bf16
typedef __attribute__((ext_vector_type(4))) float f32x4;    // MFMA accumulator
typedef __attribute__((ext_vector_type(2))) float f32x2;    // packed-math pair

__device__ __forceinline__ unsigned short f2bf(float f) {
    __hip_bfloat16 h = __float2bfloat16(f);
    return *reinterpret_cast<unsigned short*>(&h);
}

__device__ __forceinline__ short8 cvt8(float4 a, float4 b) {
    short8 r;
    r[0] = (short)f2bf(a.x); r[1] = (short)f2bf(a.y);
    r[2] = (short)f2bf(a.z); r[3] = (short)f2bf(a.w);
    r[4] = (short)f2bf(b.x); r[5] = (short)f2bf(b.y);
    r[6] = (short)f2bf(b.z); r[7] = (short)f2bf(b.w);
    return r;
}

// VALU cross-lane reduce over each 16-lane row: x += row_ror(x, N). After
// ror 8,4,2,1 every lane holds its 16-lane row sum. Pure VALU, no DS pipe.
#define DPP_ROR_ADD(x, N)                                                     \
    x += __int_as_float(__builtin_amdgcn_update_dpp(                          \
            0, __float_as_int(x), 0x120 + (N), 0xf, 0xf, false))

// ---------------------------------------------------------------------------
// W1 prep only: W1 * adjacency -> bf16 workspace. 256 blocks x 256 = 65536
// float4 chunks exactly. (X conversion is fused into the main kernel.)
// ---------------------------------------------------------------------------
__global__ __launch_bounds__(256) void w1prep_kernel(
    const float* __restrict__ W1, const float* __restrict__ adj,
    unsigned short* __restrict__ W1bf)
{
    int c = blockIdx.x * 256 + threadIdx.x;   // 0..65535
    int flat = c * 4;
    int i = flat >> 12;        // node index
    int d = flat & 63;         // within-row offset (contiguous dim)
    float4 w = reinterpret_cast<const float4*>(W1)[c];
    float4 a = *reinterpret_cast<const float4*>(adj + i * DN + d);
    ushort4 o;
    o.x = f2bf(w.x * a.x); o.y = f2bf(w.y * a.y);
    o.z = f2bf(w.z * a.z); o.w = f2bf(w.w * a.w);
    reinterpret_cast<ushort4*>(W1bf)[c] = o;
}

// ---------------------------------------------------------------------------
// Main: block = (128-row batch tile, 4 nodes). 4 waves x 32 rows.
// X loaded fp32 + converted in-register (no Xbf round-trip). W1' staged in
// LDS (XOR-swizzled). j-loop fully unrolled: compiler hoists next-j ds_reads
// over current-j epilogue. Epilogue uses packed f32x2 fma + DPP reduction.
// ---------------------------------------------------------------------------
__global__ __launch_bounds__(256, 3) void mlp_kernel(
    const float* __restrict__ X,               // [B][64] fp32
    const unsigned short* __restrict__ W1bf,   // [D][H][64] bf16 (adj folded)
    const float* __restrict__ W2,              // [D][H] fp32
    float* __restrict__ out)                   // [B][D] fp32
{
    const int btile = blockIdx.x & 127;        // fastest: X-tile L2 locality
    const int ng    = blockIdx.x >> 7;         // node group (4 nodes)
    const int wave  = threadIdx.x >> 6;        // 0..3
    const int lane  = threadIdx.x & 63;
    const int row16 = lane & 15;               // A/B frag row, C/D column (h)
    const int quad  = lane >> 4;               // A/B k-quad, C/D row-quad (b)

    __shared__ unsigned short ldsW1[4 * HN * DN];  // 32 KB, swizzled
    __shared__ float ldsW2[4 * HN];                // 1 KB
    __shared__ float lds_out[128][4];              // 2 KB

    // ---- A fragments: fp32 load + in-register bf16 convert ----
    const int b0 = btile * 128 + wave * 32;
    const float* aBase = X + (size_t)(b0 + row16) * DN + quad * 8;
    short8 afrag[2][2];
#pragma unroll
    for (int mt = 0; mt < 2; ++mt)
#pragma unroll
        for (int kk = 0; kk < 2; ++kk) {
            const float* p = aBase + mt * 16 * DN + kk * 32;
            float4 v0 = *reinterpret_cast<const float4*>(p);
            float4 v1 = *reinterpret_cast<const float4*>(p + 4);
            afrag[mt][kk] = cvt8(v0, v1);
        }

    // ---- Stage W1' (4 nodes = 2048 x 16B chunks) swizzled into LDS ----
    {
        const unsigned short* gsrc = W1bf + (size_t)ng * (4 * HN * DN);
#pragma unroll
        for (int it = 0; it < 8; ++it) {
            int chunk = it * 256 + threadIdx.x;      // 0..2047
            int nl = chunk >> 9;                     // node_local
            int rem = chunk & 511;
            int h = rem >> 3;
            int c = rem & 7;
            short8 v = *reinterpret_cast<const short8*>(gsrc + chunk * 8);
            int elem = nl * 4096 + h * 64 + ((c ^ (h & 7)) << 3);
            *reinterpret_cast<short8*>(&ldsW1[elem]) = v;
        }
        ldsW2[threadIdx.x] = W2[ng * 256 + threadIdx.x];
    }
    __syncthreads();

    // ---- j-loop: LDS-only operands, fully unrolled for cross-j overlap ----
#pragma unroll
    for (int j = 0; j < 4; ++j) {
        short8 bfrag[2][4];
#pragma unroll
        for (int kk = 0; kk < 2; ++kk)
#pragma unroll
            for (int nt = 0; nt < 4; ++nt) {
                int h = nt * 16 + row16;
                int elem = j * 4096 + h * 64 + (((kk * 4 + quad) ^ (row16 & 7)) << 3);
                bfrag[kk][nt] = *reinterpret_cast<const short8*>(&ldsW1[elem]);
            }

        float w2v[4];
#pragma unroll
        for (int nt = 0; nt < 4; ++nt)
            w2v[nt] = ldsW2[j * 64 + nt * 16 + row16];

        f32x4 acc[2][4];
#pragma unroll
        for (int mt = 0; mt < 2; ++mt)
#pragma unroll
            for (int nt = 0; nt < 4; ++nt)
                acc[mt][nt] = (f32x4){0.f, 0.f, 0.f, 0.f};

#pragma unroll
        for (int kk = 0; kk < 2; ++kk)
#pragma unroll
            for (int nt = 0; nt < 4; ++nt) {
                acc[0][nt] = __builtin_amdgcn_mfma_f32_16x16x32_bf16(afrag[0][kk], bfrag[kk][nt], acc[0][nt], 0, 0, 0);
                acc[1][nt] = __builtin_amdgcn_mfma_f32_16x16x32_bf16(afrag[1][kk], bfrag[kk][nt], acc[1][nt], 0, 0, 0);
            }

        // epilogue: out[b,node] = sum_h relu(H[b,h]) * W2[node,h]
        // C/D layout: h = nt*16 + row16, b = mt*16 + quad*4 + reg
#pragma unroll
        for (int mt = 0; mt < 2; ++mt) {
            f32x2 s01 = (f32x2){0.f, 0.f}, s23 = (f32x2){0.f, 0.f};
#pragma unroll
            for (int nt = 0; nt < 4; ++nt) {
                f32x2 m01 = (f32x2){fmaxf(acc[mt][nt][0], 0.f), fmaxf(acc[mt][nt][1], 0.f)};
                f32x2 m23 = (f32x2){fmaxf(acc[mt][nt][2], 0.f), fmaxf(acc[mt][nt][3], 0.f)};
                s01 += m01 * w2v[nt];     // v_pk_fma_f32
                s23 += m23 * w2v[nt];
            }
            float p[4] = {s01[0], s01[1], s23[0], s23[1]};
#pragma unroll
            for (int r = 0; r < 4; ++r) {
                DPP_ROR_ADD(p[r], 8);
                DPP_ROR_ADD(p[r], 4);
                DPP_ROR_ADD(p[r], 2);
                DPP_ROR_ADD(p[r], 1);
            }
            if (row16 < 4)
                lds_out[wave * 32 + mt * 16 + quad * 4 + row16][j] = p[row16];
        }
    }

    __syncthreads();
    // cooperative store: 128 rows; thread t stores row t's float4
    if (threadIdx.x < 128) {
        int row = threadIdx.x;
        float4 v = *reinterpret_cast<const float4*>(&lds_out[row][0]);
        *reinterpret_cast<float4*>(out + (size_t)(btile * 128 + row) * DN + ng * 4) = v;
    }
}

extern "C" void kernel_launch(void* const* d_in, const int* in_sizes, int n_in,
                              void* d_out, int out_size, void* d_ws, size_t ws_size,
                              hipStream_t stream) {
    const float* X   = (const float*)d_in[0];   // [B, D] fp32
    const float* adj = (const float*)d_in[1];   // [D, D] fp32
    const float* W1  = (const float*)d_in[2];   // [D, H, D] fp32
    const float* W2  = (const float*)d_in[3];   // [D, H] fp32
    float* out = (float*)d_out;                 // [B, D] fp32

    unsigned short* W1bf = (unsigned short*)d_ws;           // 512 KB

    w1prep_kernel<<<WCH / 256, 256, 0, stream>>>(W1, adj, W1bf);
    mlp_kernel<<<128 * 16, 256, 0, stream>>>(X, W1bf, W2, out);
}